// Round 1
// baseline (997.583 us; speedup 1.0000x reference)
//
#include <hip/hip_runtime.h>
#include <stdint.h>

// Problem constants
#define NB 768          // ntiles*N*f = 16*8*6 rows
#define LTILE 334       // positions per row
#define LOUT 315        // 334 - 20 + 1
#define KF 20           // motif length
#define AA 21           // alphabet
#define UU 600          // profiles
#define S_SIZE 76800    // 16*8*600
#define R_SIZE 252000   // 20*21*600

// workspace layout (bytes)
#define WS_IDS_OFF 504064                    // after Rb (252000*2 -> pad)
#define WS_PS_OFF  (504064 + 258048)         // after ids (768*336)

// ---------------- kernel 1: R = log(max(P/Q, eps)), fp32 out + bf16 copy ---
__global__ __launch_bounds__(256) void prep_R(const float* __restrict__ P,
                                              const float* __restrict__ Q,
                                              float* __restrict__ Rout,
                                              uint16_t* __restrict__ Rb) {
  int i = blockIdx.x * 256 + threadIdx.x;
  if (i >= R_SIZE) return;
  int a = (i / UU) % AA;
  float v = logf(fmaxf(P[i] / Q[a], 1e-6f));
  Rout[i] = v;
  // round-to-nearest-even bf16
  uint32_t x = __float_as_uint(v);
  uint32_t r = (x + 0x7fffu + ((x >> 16) & 1u)) >> 16;
  Rb[i] = (uint16_t)r;
}

// ---------------- kernel 2: one-hot -> letter ids (bytes, rows padded to 336)
__global__ __launch_bounds__(256) void prep_ids(const float* __restrict__ X,
                                                uint8_t* __restrict__ ids) {
  int b = blockIdx.x;
  for (int pos = threadIdx.x; pos < 336; pos += 256) {
    uint8_t id = 0;
    if (pos < LTILE) {
      const float* xp = X + ((size_t)b * LTILE + pos) * AA;
#pragma unroll
      for (int a = 0; a < AA; a++)
        if (xp[a] > 0.5f) id = (uint8_t)a;
    }
    ids[b * 336 + pos] = id;  // bytes 334/335 -> 0 (window padding)
  }
}

// ---------------- kernel 3: Z gather + per-(b,u) partial max ---------------
// grid = (768, 10); block = 256 = 8 u-octs x 32 l-groups; u-chunk = 64.
// LDS: R slice re-laid as [slot(8)][row(420)][8 bf16] = 53760 B exactly.
//  - 53760 B <= 54613 -> 3 blocks/CU (12 waves/CU) vs previous 60928 B / 2.
//  - per-thread panel base Rs = Rl + uoct*420*8; read addr = Rs + (c<<4) bytes
//    with w*336 folded into the ds_read offset immediate -> 2 VALU/iter addr.
//  - row stride 16 B: rows congruent mod 8 share banks (~2.6 extra cyc/read,
//    same class structure as the old 144-B padded layout).
// ids window dwords come straight from global (L1-resident 336-B row); the
// old idl LDS buffer is dropped to keep LDS under the 3-block threshold.
__global__ __launch_bounds__(256) void zmain(const uint16_t* __restrict__ Rb,
                                             const uint8_t* __restrict__ ids,
                                             float* __restrict__ Z,
                                             float* __restrict__ pS) {
  __shared__ uint16_t Rl[8 * 420 * 8];  // 53760 B
  int b = blockIdx.x;
  int u0 = blockIdx.y * 64;
  int uw = min(64, UU - u0);   // 64, last chunk 24
  int tid = threadIdx.x;

  // stage R slice: segment seg (8 bf16) of row -> panel seg, slot [row][0..7]
  int nseg = uw >> 3;          // 8 or 3
  if (nseg == 8) {
    for (int i = tid; i < 420 * 8; i += 256) {
      int row = i >> 3, seg = i & 7;
      *(uint4*)(&Rl[(seg * 420 + row) * 8]) =
          *(const uint4*)(Rb + row * UU + u0 + seg * 8);
    }
  } else {
    for (int i = tid; i < 420 * 3; i += 256) {
      int row = i / 3, seg = i - row * 3;
      *(uint4*)(&Rl[(seg * 420 + row) * 8]) =
          *(const uint4*)(Rb + row * UU + u0 + seg * 8);
    }
  }
  __syncthreads();

  int uoct = tid >> 5;   // 0..7 : which 8 u's
  int lgrp = tid & 31;   // 0..31: which l block
  if (uoct * 8 >= uw) return;          // idle octs in tail chunk (no more barriers)
  int uoff = uoct * 8;

  const uint16_t* Rs = Rl + uoct * (420 * 8);   // this oct's 6720-B panel
  const uint8_t* idb = ids + b * 336;

  float smax[8];
#pragma unroll
  for (int k = 0; k < 8; k++) smax[k] = -3.4e38f;

  float* Zb = Z + (size_t)b * (LOUT * UU) + u0 + uoff;

  for (int jj = 0; jj < 3; jj++) {
    int l0 = jj * 128 + lgrp * 4;      // 4 consecutive l per thread per pass
    if (l0 >= LOUT) break;
    // ids window l0..l0+23 into 6 dwords (4-aligned global loads, L1-hit)
    uint32_t idw[6];
#pragma unroll
    for (int d = 0; d < 6; d++)
      idw[d] = *(const uint32_t*)(idb + l0 + 4 * d);

    float acc[4][8];
#pragma unroll
    for (int g = 0; g < 4; g++)
#pragma unroll
      for (int k = 0; k < 8; k++) acc[g][k] = 0.0f;

#pragma unroll
    for (int w = 0; w < KF; w++) {
#pragma unroll
      for (int g = 0; g < 4; g++) {
        int p = w + g;
        uint32_t c = (idw[p >> 2] >> ((p & 3) * 8)) & 0xFFu;
        // ushort index: c*8 (reg) + w*168 (folds to ds offset imm w*336 B)
        const uint4 rv = *(const uint4*)(Rs + c * 8 + w * 168);
        acc[g][0] += __uint_as_float(rv.x << 16);
        acc[g][1] += __uint_as_float(rv.x & 0xffff0000u);
        acc[g][2] += __uint_as_float(rv.y << 16);
        acc[g][3] += __uint_as_float(rv.y & 0xffff0000u);
        acc[g][4] += __uint_as_float(rv.z << 16);
        acc[g][5] += __uint_as_float(rv.z & 0xffff0000u);
        acc[g][6] += __uint_as_float(rv.w << 16);
        acc[g][7] += __uint_as_float(rv.w & 0xffff0000u);
      }
    }
#pragma unroll
    for (int g = 0; g < 4; g++) {
      int l = l0 + g;
      if (l < LOUT) {
        float* zp = Zb + (size_t)l * UU;
        float4 a0 = make_float4(acc[g][0], acc[g][1], acc[g][2], acc[g][3]);
        float4 a1 = make_float4(acc[g][4], acc[g][5], acc[g][6], acc[g][7]);
        *(float4*)zp = a0;
        *(float4*)(zp + 4) = a1;
#pragma unroll
        for (int k = 0; k < 8; k++) smax[k] = fmaxf(smax[k], acc[g][k]);
      }
    }
  }

  // reduce max over the 32 l-groups (same uoct == same 32-lane subgroup)
#pragma unroll
  for (int k = 0; k < 8; k++) {
    float v = smax[k];
#pragma unroll
    for (int off = 16; off >= 1; off >>= 1)
      v = fmaxf(v, __shfl_down(v, off, 32));
    if (lgrp == 0) pS[b * UU + u0 + uoff + k] = v;
  }
}

// ---------------- kernel 4: S = max over f of partial maxes ----------------
__global__ __launch_bounds__(256) void finalS(const float* __restrict__ pS,
                                              float* __restrict__ S) {
  int i = blockIdx.x * 256 + threadIdx.x;
  if (i >= S_SIZE) return;
  int u = i % UU;
  int tn = i / UU;
  float m = -3.4e38f;
#pragma unroll
  for (int f = 0; f < 6; f++) m = fmaxf(m, pS[(tn * 6 + f) * UU + u]);
  S[i] = m;
}

extern "C" void kernel_launch(void* const* d_in, const int* in_sizes, int n_in,
                              void* d_out, int out_size, void* d_ws, size_t ws_size,
                              hipStream_t stream) {
  const float* X = (const float*)d_in[0];
  const float* P = (const float*)d_in[1];
  const float* Q = (const float*)d_in[2];
  float* S = (float*)d_out;
  float* R = S + S_SIZE;
  float* Z = R + R_SIZE;
  uint16_t* Rb = (uint16_t*)d_ws;
  uint8_t* ids = (uint8_t*)d_ws + WS_IDS_OFF;
  float* pS = (float*)((uint8_t*)d_ws + WS_PS_OFF);

  hipLaunchKernelGGL(prep_R, dim3((R_SIZE + 255) / 256), dim3(256), 0, stream,
                     P, Q, R, Rb);
  hipLaunchKernelGGL(prep_ids, dim3(NB), dim3(256), 0, stream, X, ids);
  hipLaunchKernelGGL(zmain, dim3(NB, 10), dim3(256), 0, stream, Rb, ids, Z, pS);
  hipLaunchKernelGGL(finalS, dim3((S_SIZE + 255) / 256), dim3(256), 0, stream,
                     pS, S);
}

// Round 2
// 932.636 us; speedup vs baseline: 1.0696x; 1.0696x over previous
//
#include <hip/hip_runtime.h>
#include <stdint.h>

// Problem constants
#define NB 768          // ntiles*N*f = 16*8*6 rows
#define LTILE 334       // positions per row
#define LOUT 315        // 334 - 20 + 1
#define KF 20           // motif length
#define AA 21           // alphabet
#define UU 600          // profiles
#define S_SIZE 76800    // 16*8*600
#define R_SIZE 252000   // 20*21*600

#define NDG 441         // 21*21 digrams
#define NW2 10          // KF/2 digram slots
#define TROWS (NW2 * NDG)   // 4410 table rows
#define UCH 75          // 600/8 u-chunks
#define BGRP 96         // 768/8 b-groups

// workspace layout (bytes)
// R2c: [75][4410][8] bf16 (u-chunk-major, contiguous 70,560-B slices) = 5,292,000
// dig: [768][336] uint16 = 516,096
// pS : [768][600] f32   = 1,843,200
#define WS_R2C_OFF 0
#define WS_DIG_OFF 5292032
#define WS_PS_OFF  (5292032 + 516096)

typedef float v2f __attribute__((ext_vector_type(2)));

__device__ __forceinline__ uint32_t bf16rne(float v) {
  uint32_t x = __float_as_uint(v);
  return (x + 0x7fffu + ((x >> 16) & 1u)) >> 16;
}

// ---------------- kernel 1: R = log(max(P/Q, eps)), fp32 out ---------------
__global__ __launch_bounds__(256) void prep_R(const float* __restrict__ P,
                                              const float* __restrict__ Q,
                                              float* __restrict__ Rout) {
  int i = blockIdx.x * 256 + threadIdx.x;
  if (i >= R_SIZE) return;
  int a = (i / UU) % AA;
  Rout[i] = logf(fmaxf(P[i] / Q[a], 1e-6f));
}

// ---------------- kernel 1b: digram table R2 (bf16) ------------------------
// R2c[uc][w2*441 + c1*21+c2][j] = bf16( R[2w2][c1][uc*8+j] + R[2w2+1][c2][uc*8+j] )
// Summed in f32 from the f32 R -> 10 roundings per output instead of 20.
__global__ __launch_bounds__(256) void prep_R2(const float* __restrict__ Rout,
                                               uint16_t* __restrict__ R2c) {
  int t = blockIdx.x * 256 + threadIdx.x;
  if (t >= UCH * TROWS) return;
  int uc = t / TROWS;
  int i = t - uc * TROWS;        // w2*441 + c12
  int w2 = i / NDG;
  int c12 = i - w2 * NDG;
  int c1 = c12 / AA;
  int c2 = c12 - c1 * AA;
  const float* pa = Rout + ((2 * w2) * AA + c1) * UU + uc * 8;
  const float* pb = Rout + ((2 * w2 + 1) * AA + c2) * UU + uc * 8;
  float4 a0 = *(const float4*)pa, a1 = *(const float4*)(pa + 4);
  float4 b0 = *(const float4*)pb, b1 = *(const float4*)(pb + 4);
  uint32_t r0 = bf16rne(a0.x + b0.x), r1 = bf16rne(a0.y + b0.y);
  uint32_t r2 = bf16rne(a0.z + b0.z), r3 = bf16rne(a0.w + b0.w);
  uint32_t r4 = bf16rne(a1.x + b1.x), r5 = bf16rne(a1.y + b1.y);
  uint32_t r6 = bf16rne(a1.z + b1.z), r7 = bf16rne(a1.w + b1.w);
  uint4 out;
  out.x = r0 | (r1 << 16);
  out.y = r2 | (r3 << 16);
  out.z = r4 | (r5 << 16);
  out.w = r6 | (r7 << 16);
  *(uint4*)(R2c + (size_t)t * 8) = out;
}

// ---------------- kernel 2: one-hot -> digram codes (uint16, rows 336) -----
__global__ __launch_bounds__(256) void prep_ids(const float* __restrict__ X,
                                                uint16_t* __restrict__ dig) {
  __shared__ uint8_t idl[336];
  int b = blockIdx.x;
  for (int pos = threadIdx.x; pos < 336; pos += 256) {
    uint8_t id = 0;
    if (pos < LTILE) {
      const float* xp = X + ((size_t)b * LTILE + pos) * AA;
#pragma unroll
      for (int a = 0; a < AA; a++)
        if (xp[a] > 0.5f) id = (uint8_t)a;
    }
    idl[pos] = id;
  }
  __syncthreads();
  for (int p = threadIdx.x; p < 336; p += 256) {
    uint16_t d = 0;
    if (p < 335) d = (uint16_t)(idl[p] * AA + idl[p + 1]);
    dig[b * 336 + p] = d;  // p=334 pairs with pad 0; never consumed for valid l
  }
}

// ---------------- kernel 3: Z gather via digram table ----------------------
// grid = (96 b-groups, 75 u-chunks); block = 256 = 8 b-slots x 32 l-groups.
// LDS: digram table slice [10][441][8u] bf16 = 70,560 B + dig rows 5,376 B.
// Per output octet: 10 gathers (vs 20) -> halves LDS reads AND unpack VALU.
__global__ __launch_bounds__(256) void zmain(const uint16_t* __restrict__ R2c,
                                             const uint16_t* __restrict__ dig,
                                             float* __restrict__ Z,
                                             float* __restrict__ pS) {
  __shared__ __align__(16) uint16_t Tl[TROWS * 8];   // 70,560 B
  __shared__ __align__(16) uint16_t digl[8 * 336];   // 5,376 B
  int b0 = blockIdx.x * 8;
  int u0 = blockIdx.y * 8;
  int tid = threadIdx.x;

  // stage table slice: contiguous 70,560 B, fully coalesced 16-B/lane
  const uint16_t* Tsrc = R2c + (size_t)blockIdx.y * (TROWS * 8);
  for (int i = tid; i < TROWS; i += 256)
    *(uint4*)(&Tl[i * 8]) = *(const uint4*)(Tsrc + i * 8);
  // stage 8 contiguous dig rows (5,376 B linear)
  const uint32_t* dsrc = (const uint32_t*)(dig + (size_t)b0 * 336);
  for (int i = tid; i < 1344; i += 256) ((uint32_t*)digl)[i] = dsrc[i];
  __syncthreads();

  int bslot = tid >> 5;   // 0..7: which b row
  int lgrp = tid & 31;    // 0..31: which l block
  int b = b0 + bslot;
  const uint16_t* dl = digl + bslot * 336;

  float smax[8];
#pragma unroll
  for (int k = 0; k < 8; k++) smax[k] = -3.4e38f;

  float* Zb = Z + (size_t)b * (LOUT * UU) + u0;

  for (int jj = 0; jj < 3; jj++) {
    int l0 = jj * 128 + lgrp * 4;      // multiple of 4
    if (l0 >= LOUT) break;
    // dig window l0..l0+21 -> 12 dwords (22 entries used), 8-B aligned loads
    uint32_t idw[12];
    const uint32_t* dwp = (const uint32_t*)(dl + l0);
#pragma unroll
    for (int d = 0; d < 6; d++) {
      uint2 t = *(const uint2*)(dwp + 2 * d);
      idw[2 * d] = t.x;
      idw[2 * d + 1] = t.y;
    }

    v2f acc[4][4];
#pragma unroll
    for (int g = 0; g < 4; g++)
#pragma unroll
      for (int d = 0; d < 4; d++) acc[g][d] = (v2f){0.0f, 0.0f};

#pragma unroll
    for (int w2 = 0; w2 < NW2; w2++) {
#pragma unroll
      for (int g = 0; g < 4; g++) {
        int r = 2 * w2 + g;                       // compile-time
        uint32_t wv = idw[r >> 1];
        uint32_t c = (r & 1) ? (wv >> 16) : (wv & 0xFFFFu);
        // byte addr = (c<<4) + w2*7056 (imm offset <= 63,504)
        const uint4 rv = *(const uint4*)(&Tl[(w2 * NDG + c) * 8]);
        v2f t0 = {__uint_as_float(rv.x << 16), __uint_as_float(rv.x & 0xffff0000u)};
        v2f t1 = {__uint_as_float(rv.y << 16), __uint_as_float(rv.y & 0xffff0000u)};
        v2f t2 = {__uint_as_float(rv.z << 16), __uint_as_float(rv.z & 0xffff0000u)};
        v2f t3 = {__uint_as_float(rv.w << 16), __uint_as_float(rv.w & 0xffff0000u)};
        acc[g][0] += t0;
        acc[g][1] += t1;
        acc[g][2] += t2;
        acc[g][3] += t3;
      }
    }
#pragma unroll
    for (int g = 0; g < 4; g++) {
      int l = l0 + g;
      if (l < LOUT) {
        float* zp = Zb + (size_t)l * UU;
        float4 a0 = make_float4(acc[g][0][0], acc[g][0][1], acc[g][1][0], acc[g][1][1]);
        float4 a1 = make_float4(acc[g][2][0], acc[g][2][1], acc[g][3][0], acc[g][3][1]);
        *(float4*)zp = a0;
        *(float4*)(zp + 4) = a1;
        smax[0] = fmaxf(smax[0], a0.x);
        smax[1] = fmaxf(smax[1], a0.y);
        smax[2] = fmaxf(smax[2], a0.z);
        smax[3] = fmaxf(smax[3], a0.w);
        smax[4] = fmaxf(smax[4], a1.x);
        smax[5] = fmaxf(smax[5], a1.y);
        smax[6] = fmaxf(smax[6], a1.z);
        smax[7] = fmaxf(smax[7], a1.w);
      }
    }
  }

  // reduce max over the 32 l-groups (lanes 0-31 / 32-63 are separate bslots)
#pragma unroll
  for (int k = 0; k < 8; k++) {
    float v = smax[k];
#pragma unroll
    for (int off = 16; off >= 1; off >>= 1)
      v = fmaxf(v, __shfl_down(v, off, 32));
    if (lgrp == 0) pS[(size_t)b * UU + u0 + k] = v;
  }
}

// ---------------- kernel 4: S = max over f of partial maxes ----------------
__global__ __launch_bounds__(256) void finalS(const float* __restrict__ pS,
                                              float* __restrict__ S) {
  int i = blockIdx.x * 256 + threadIdx.x;
  if (i >= S_SIZE) return;
  int u = i % UU;
  int tn = i / UU;
  float m = -3.4e38f;
#pragma unroll
  for (int f = 0; f < 6; f++) m = fmaxf(m, pS[(tn * 6 + f) * UU + u]);
  S[i] = m;
}

extern "C" void kernel_launch(void* const* d_in, const int* in_sizes, int n_in,
                              void* d_out, int out_size, void* d_ws, size_t ws_size,
                              hipStream_t stream) {
  const float* X = (const float*)d_in[0];
  const float* P = (const float*)d_in[1];
  const float* Q = (const float*)d_in[2];
  float* S = (float*)d_out;
  float* R = S + S_SIZE;
  float* Z = R + R_SIZE;
  uint16_t* R2c = (uint16_t*)d_ws;
  uint16_t* digW = (uint16_t*)((uint8_t*)d_ws + WS_DIG_OFF);
  float* pS = (float*)((uint8_t*)d_ws + WS_PS_OFF);

  hipLaunchKernelGGL(prep_R, dim3((R_SIZE + 255) / 256), dim3(256), 0, stream,
                     P, Q, R);
  hipLaunchKernelGGL(prep_ids, dim3(NB), dim3(256), 0, stream, X, digW);
  hipLaunchKernelGGL(prep_R2, dim3((UCH * TROWS + 255) / 256), dim3(256), 0,
                     stream, R, R2c);
  hipLaunchKernelGGL(zmain, dim3(BGRP, UCH), dim3(256), 0, stream, R2c, digW,
                     Z, pS);
  hipLaunchKernelGGL(finalS, dim3((S_SIZE + 255) / 256), dim3(256), 0, stream,
                     pS, S);
}

// Round 4
// 804.780 us; speedup vs baseline: 1.2396x; 1.1589x over previous
//
#include <hip/hip_runtime.h>
#include <stdint.h>

// Problem constants
#define NB 768          // ntiles*N*f = 16*8*6 rows
#define LTILE 334       // positions per row
#define LOUT 315        // 334 - 20 + 1
#define KF 20           // motif length
#define AA 21           // alphabet
#define UU 600          // profiles
#define S_SIZE 76800    // 16*8*600
#define R_SIZE 252000   // 20*21*600
#define NROWS 420       // KF*AA table rows

// workspace layout (bytes)
#define WS_IDS_OFF 504064                    // after Rb (252000*2 -> pad)
#define WS_PS_OFF  (504064 + 258112)         // after ids (768*336 + 64 pad)

typedef float v2f __attribute__((ext_vector_type(2)));

// ---------------- kernel 1: R = log(max(P/Q, eps)), fp32 out + bf16 copy ---
__global__ __launch_bounds__(256) void prep_R(const float* __restrict__ P,
                                              const float* __restrict__ Q,
                                              float* __restrict__ Rout,
                                              uint16_t* __restrict__ Rb) {
  int i = blockIdx.x * 256 + threadIdx.x;
  if (i >= R_SIZE) return;
  int a = (i / UU) % AA;
  float v = logf(fmaxf(P[i] / Q[a], 1e-6f));
  Rout[i] = v;
  uint32_t x = __float_as_uint(v);
  uint32_t r = (x + 0x7fffu + ((x >> 16) & 1u)) >> 16;
  Rb[i] = (uint16_t)r;
}

// ---------------- kernel 2: one-hot -> letter ids (bytes, rows padded 336) -
__global__ __launch_bounds__(256) void prep_ids(const float* __restrict__ X,
                                                uint8_t* __restrict__ ids) {
  int b = blockIdx.x;
  for (int pos = threadIdx.x; pos < 336; pos += 256) {
    uint8_t id = 0;
    if (pos < LTILE) {
      const float* xp = X + ((size_t)b * LTILE + pos) * AA;
#pragma unroll
      for (int a = 0; a < AA; a++)
        if (xp[a] > 0.5f) id = (uint8_t)a;
    }
    ids[b * 336 + pos] = id;  // bytes 334/335 -> 0 (window padding)
  }
}

// ---------------- kernel 3: Z gather, u-fast lane mapping ------------------
// grid = (768 b, 10 u-groups of 64); block = 256 = 4 waves.
// Wave lane map: seg = lane&7 (8-u chunk), lrow = lane>>3 (l row).
// LDS table Tl[420][64] bf16 = 53,760 B -> 3 blocks/CU.
//  - gather: one wave b128 = 8 rows x contiguous 128-B row-slices: every row
//    slice covers all 32 banks exactly once -> conflict-free regardless of
//    the data-dependent row indices.
//  - store: lanes 0..7 cover u0..u0+63 of one l -> wave store = 8 l-rows x
//    256-B contiguous spans; block covers full 64-u span -> no write amp.
__global__ __launch_bounds__(256, 3) void zmain(const uint16_t* __restrict__ Rb,
                                                const uint8_t* __restrict__ ids,
                                                float* __restrict__ Z,
                                                float* __restrict__ pS) {
  __shared__ __align__(16) uint16_t Tl[NROWS * 64];  // 53,760 B (reused below)
  int b = blockIdx.x;
  int u0 = blockIdx.y * 64;
  int uw = min(64, UU - u0);       // 64, tail 24
  int nseg = uw >> 3;              // 8 or 3
  int tid = threadIdx.x;

  // stage table slice: row-slices of nseg*16 B, fully coalesced
  for (int i = tid; i < NROWS * nseg; i += 256) {
    int row = i / nseg, seg = i - row * nseg;
    *(uint4*)(&Tl[row * 64 + seg * 8]) =
        *(const uint4*)(Rb + row * UU + u0 + seg * 8);
  }
  __syncthreads();

  int wave = tid >> 6;
  int lane = tid & 63;
  int seg = lane & 7;
  int lrow = lane >> 3;
  bool segok = seg < nseg;
  const uint8_t* idb = ids + b * 336;
  const char* Tseg = (const char*)Tl + seg * 16;   // + c*128 + w*2688

  v2f sm[4];
#pragma unroll
  for (int d = 0; d < 4; d++) sm[d] = (v2f){-3.4e38f, -3.4e38f};

  for (int pass = 0; pass < 10; pass++) {
    int l = pass * 32 + wave * 8 + lrow;
    if (l < LOUT && segok) {
      // window bytes ids[l..l+19]: 6 aligned dwords + 64-bit funnel shift
      int al = l & ~3;
      int sh = (l & 3) * 8;
      const uint32_t* wp = (const uint32_t*)(idb + al);
      uint32_t raw[6];
#pragma unroll
      for (int j = 0; j < 6; j++) raw[j] = wp[j];
      uint32_t W[5];
#pragma unroll
      for (int j = 0; j < 5; j++)
        W[j] = (uint32_t)((((uint64_t)raw[j + 1] << 32) | raw[j]) >> sh);

      v2f acc[4];
#pragma unroll
      for (int d = 0; d < 4; d++) acc[d] = (v2f){0.0f, 0.0f};

#pragma unroll
      for (int w = 0; w < KF; w++) {
        uint32_t c = (W[w >> 2] >> ((w & 3) * 8)) & 0xFFu;
        // byte addr = seg*16 + c*128 + (imm) w*2688  (max 53,744 < 64 KB)
        const uint4 rv = *(const uint4*)(Tseg + (c << 7) + w * 2688);
        acc[0] += (v2f){__uint_as_float(rv.x << 16),
                        __uint_as_float(rv.x & 0xffff0000u)};
        acc[1] += (v2f){__uint_as_float(rv.y << 16),
                        __uint_as_float(rv.y & 0xffff0000u)};
        acc[2] += (v2f){__uint_as_float(rv.z << 16),
                        __uint_as_float(rv.z & 0xffff0000u)};
        acc[3] += (v2f){__uint_as_float(rv.w << 16),
                        __uint_as_float(rv.w & 0xffff0000u)};
      }

      float* zp = Z + ((size_t)b * LOUT + l) * UU + u0 + seg * 8;
      *(float4*)zp = make_float4(acc[0][0], acc[0][1], acc[1][0], acc[1][1]);
      *(float4*)(zp + 4) =
          make_float4(acc[2][0], acc[2][1], acc[3][0], acc[3][1]);
#pragma unroll
      for (int d = 0; d < 4; d++) {
        sm[d][0] = fmaxf(sm[d][0], acc[d][0]);
        sm[d][1] = fmaxf(sm[d][1], acc[d][1]);
      }
    }
  }

  // reduce max over the 8 lrow lanes (xor flips bits 3..5 only; seg preserved)
#pragma unroll
  for (int d = 0; d < 4; d++) {
#pragma unroll
    for (int off = 8; off <= 32; off <<= 1) {
      sm[d][0] = fmaxf(sm[d][0], __shfl_xor(sm[d][0], off));
      sm[d][1] = fmaxf(sm[d][1], __shfl_xor(sm[d][1], off));
    }
  }

  // cross-wave reduce through Tl (table no longer needed)
  __syncthreads();
  float* red = (float*)Tl;   // [4 waves][64 u] f32
  if (lane < 8) {            // lane==seg, lrow==0: holds wave max for its seg
    float* rp = red + wave * 64 + lane * 8;
    *(float4*)rp = make_float4(sm[0][0], sm[0][1], sm[1][0], sm[1][1]);
    *(float4*)(rp + 4) = make_float4(sm[2][0], sm[2][1], sm[3][0], sm[3][1]);
  }
  __syncthreads();
  if (tid < 64 && tid < uw) {
    float v = red[tid];
#pragma unroll
    for (int w2 = 1; w2 < 4; w2++) v = fmaxf(v, red[w2 * 64 + tid]);
    pS[(size_t)b * UU + u0 + tid] = v;
  }
}

// ---------------- kernel 4: S = max over f of partial maxes ----------------
__global__ __launch_bounds__(256) void finalS(const float* __restrict__ pS,
                                              float* __restrict__ S) {
  int i = blockIdx.x * 256 + threadIdx.x;
  if (i >= S_SIZE) return;
  int u = i % UU;
  int tn = i / UU;
  float m = -3.4e38f;
#pragma unroll
  for (int f = 0; f < 6; f++) m = fmaxf(m, pS[(tn * 6 + f) * UU + u]);
  S[i] = m;
}

extern "C" void kernel_launch(void* const* d_in, const int* in_sizes, int n_in,
                              void* d_out, int out_size, void* d_ws, size_t ws_size,
                              hipStream_t stream) {
  const float* X = (const float*)d_in[0];
  const float* P = (const float*)d_in[1];
  const float* Q = (const float*)d_in[2];
  float* S = (float*)d_out;
  float* R = S + S_SIZE;
  float* Z = R + R_SIZE;
  uint16_t* Rb = (uint16_t*)d_ws;
  uint8_t* ids = (uint8_t*)d_ws + WS_IDS_OFF;
  float* pS = (float*)((uint8_t*)d_ws + WS_PS_OFF);

  hipLaunchKernelGGL(prep_R, dim3((R_SIZE + 255) / 256), dim3(256), 0, stream,
                     P, Q, R, Rb);
  hipLaunchKernelGGL(prep_ids, dim3(NB), dim3(256), 0, stream, X, ids);
  hipLaunchKernelGGL(zmain, dim3(NB, 10), dim3(256), 0, stream, Rb, ids, Z, pS);
  hipLaunchKernelGGL(finalS, dim3((S_SIZE + 255) / 256), dim3(256), 0, stream,
                     pS, S);
}